// Round 7
// baseline (546.849 us; speedup 1.0000x reference)
//
#include <hip/hip_runtime.h>

typedef unsigned short u16;
typedef unsigned int u32;
typedef unsigned long long u64;
typedef __attribute__((ext_vector_type(8))) short short8;
typedef __attribute__((ext_vector_type(4))) float f32x4;

#define BSHIFT 8               // 256 rows per bucket
#define MAXBUCK 512

__device__ __forceinline__ float bf2f(u32 u) {
    union { u32 i; float f; } v; v.i = u << 16; return v.f;
}
__device__ __forceinline__ u16 f2bf(float f) {
    union { float f; u32 i; } v; v.f = f;
    u32 u = (v.i + 0x7fffu + ((v.i >> 16) & 1u)) >> 16;
    return (u16)u;
}

// ---------------- cast x (fp32) -> Xb (packed bf16 pairs, row-major) ----------------
__global__ void k_cast(const float4* __restrict__ X, u32* __restrict__ Xb, long total4) {
    long i = (long)blockIdx.x * blockDim.x + threadIdx.x;
    long stride = (long)gridDim.x * blockDim.x;
    for (; i < total4; i += stride) {
        float4 p = X[i];
        Xb[i * 2 + 0] = (u32)f2bf(p.x) | ((u32)f2bf(p.y) << 16);
        Xb[i * 2 + 1] = (u32)f2bf(p.z) | ((u32)f2bf(p.w) << 16);
    }
}

// ---------------- prep weights: fp32 [128 x Hout] row-major -> bf16 MFMA-B-fragment packed ----------------
__global__ void k_prepW(const float* __restrict__ W0, const float* __restrict__ W1,
                        const float* __restrict__ W2, const float* __restrict__ W3,
                        const float* __restrict__ W4, const float* __restrict__ W5,
                        u16* __restrict__ Wp1, u16* __restrict__ Wp2) {
    int m = blockIdx.y;
    const float* W = (m == 0) ? W0 : (m == 1) ? W1 : (m == 2) ? W2 : (m == 3) ? W3 : (m == 4) ? W4 : W5;
    int Hout = (m < 3) ? 128 : 64;
    u16* dst = (m < 3) ? (Wp1 + m * 128 * 128) : (Wp2 + (m - 3) * 64 * 128);
    int total = 128 * Hout;
    for (int i = blockIdx.x * blockDim.x + threadIdx.x; i < total; i += gridDim.x * blockDim.x) {
        int T = i / 2048;
        int c = (i / 512) & 3;
        int lane = (i / 8) & 63;
        int j = i & 7;
        int col = T * 16 + (lane & 15);
        int k = c * 32 + (lane >> 4) * 8 + j;
        dst[i] = f2bf(W[k * Hout + col]);
    }
}

// ---------------- CSR build: degree + row_ptr scan ----------------
__global__ void k_deg(const int* __restrict__ erow, int e, int* __restrict__ deg) {
    int i = blockIdx.x * blockDim.x + threadIdx.x;
    if (i < e) atomicAdd(&deg[erow[i]], 1);
}

__global__ void k_scan_a(const int* __restrict__ deg, int n, int* __restrict__ bsum) {
    __shared__ int lds[256];
    int b = blockIdx.x, t = threadIdx.x;
    int base = b * 1024;
    int s = 0;
    for (int i = t; i < 1024; i += 256) { int idx = base + i; if (idx < n) s += deg[idx]; }
    lds[t] = s; __syncthreads();
    for (int off = 128; off > 0; off >>= 1) { if (t < off) lds[t] += lds[t + off]; __syncthreads(); }
    if (t == 0) bsum[b] = lds[0];
}

__global__ void k_scan_b(const int* __restrict__ bsum, int nb, int* __restrict__ boff) {
    __shared__ int lds[256];
    int t = threadIdx.x;
    int v = (t < nb) ? bsum[t] : 0;
    lds[t] = v; __syncthreads();
    for (int off = 1; off < 256; off <<= 1) {
        int x = (t >= off) ? lds[t - off] : 0;
        __syncthreads();
        lds[t] += x;
        __syncthreads();
    }
    if (t < nb) boff[t] = lds[t] - v;
}

__global__ void k_scan_c(const int* __restrict__ deg, int n, const int* __restrict__ boff,
                         int* __restrict__ row_ptr, float* __restrict__ inv_deg) {
    __shared__ int lds[256];
    int b = blockIdx.x, t = threadIdx.x;
    int base = b * 1024 + t * 4;
    int v0 = 0, v1 = 0, v2 = 0, v3 = 0;
    if (base + 0 < n) v0 = deg[base + 0];
    if (base + 1 < n) v1 = deg[base + 1];
    if (base + 2 < n) v2 = deg[base + 2];
    if (base + 3 < n) v3 = deg[base + 3];
    int s = v0 + v1 + v2 + v3;
    lds[t] = s; __syncthreads();
    for (int off = 1; off < 256; off <<= 1) {
        int x = (t >= off) ? lds[t - off] : 0;
        __syncthreads();
        lds[t] += x;
        __syncthreads();
    }
    int run = boff[b] + lds[t] - s;
    if (base + 0 < n) { row_ptr[base + 0] = run; inv_deg[base + 0] = v0 > 0 ? 1.f / v0 : 0.f; run += v0; }
    if (base + 1 < n) { row_ptr[base + 1] = run; inv_deg[base + 1] = v1 > 0 ? 1.f / v1 : 0.f; run += v1; }
    if (base + 2 < n) { row_ptr[base + 2] = run; inv_deg[base + 2] = v2 > 0 ? 1.f / v2 : 0.f; run += v2; }
    if (base + 3 < n) { row_ptr[base + 3] = run; inv_deg[base + 3] = v3 > 0 ? 1.f / v3 : 0.f; run += v3; }
    if (b == gridDim.x - 1 && t == 255) row_ptr[n] = run;
}

// ---------------- bucketed edge sort ----------------
// Bucket offsets in bedge-space == row_ptr at bucket boundaries (same cumulative layout).
__global__ void k_ginit(const int* __restrict__ row_ptr, int n, int nbuck, int* __restrict__ gcursor) {
    int b = blockIdx.x * blockDim.x + threadIdx.x;
    if (b < nbuck) {
        int r = b << BSHIFT;
        gcursor[b] = row_ptr[r < n ? r : n];
    }
}

// Scatter edges into bucket-major array; per-(block,bucket) contiguous reserved runs.
__global__ void k_bscatter(const int* __restrict__ erow, const int* __restrict__ ecol, int e,
                           int nbuck, int* __restrict__ gcursor, u64* __restrict__ bedge) {
    __shared__ int hist[MAXBUCK];
    __shared__ int base[MAXBUCK];
    for (int t = threadIdx.x; t < nbuck; t += blockDim.x) hist[t] = 0;
    __syncthreads();
    int chunk = (e + gridDim.x - 1) / gridDim.x;
    int lo = blockIdx.x * chunk, hi = min(e, lo + chunk);
    for (int i = lo + threadIdx.x; i < hi; i += blockDim.x)
        atomicAdd(&hist[erow[i] >> BSHIFT], 1);
    __syncthreads();
    for (int t = threadIdx.x; t < nbuck; t += blockDim.x) {
        int c = hist[t];
        base[t] = c ? atomicAdd(&gcursor[t], c) : 0;
        hist[t] = 0;
    }
    __syncthreads();
    for (int i = lo + threadIdx.x; i < hi; i += blockDim.x) {
        int r = erow[i];
        int bk = r >> BSHIFT;
        int pos = base[bk] + atomicAdd(&hist[bk], 1);
        bedge[pos] = (u64)(u32)ecol[i] << 32 | (u32)r;
    }
}

// One workgroup per bucket; LDS cursors; cols writes confined to this bucket's ~16KB window.
__global__ void k_bfill(const u64* __restrict__ bedge, const int* __restrict__ row_ptr, int n,
                        int* __restrict__ cols) {
    __shared__ int cur[1 << BSHIFT];
    int b = blockIdx.x;
    for (int t = threadIdx.x; t < (1 << BSHIFT); t += blockDim.x) cur[t] = 0;
    __syncthreads();
    int rbase = b << BSHIFT;
    int rend = min(n, rbase + (1 << BSHIFT));
    int lo = row_ptr[rbase], hi = row_ptr[rend];
    for (int i = lo + threadIdx.x; i < hi; i += blockDim.x) {
        u64 v = bedge[i];
        int r = (int)(u32)v;
        int c = (int)(v >> 32);
        int p = row_ptr[r] + atomicAdd(&cur[r - rbase], 1);
        cols[p] = c;
    }
}

// ---------------- SpMM: bf16 X row-major in; A-fragment-packed S, D, X out ----------------
// Scalar (wave-uniform) cols loads -> s_load; 8 independent global gathers in flight.
__global__ void k_spmm(const u32* __restrict__ X2, const int* __restrict__ row_ptr,
                       const int* __restrict__ cols, const float* __restrict__ inv_deg,
                       u32* __restrict__ Sp, u32* __restrict__ Dp, u32* __restrict__ Xp, int n) {
    int w = (int)((blockIdx.x * blockDim.x + threadIdx.x) >> 6);
    if (w >= n) return;
    int lane = threadIdx.x & 63;
    int beg = row_ptr[w], end = row_ptr[w + 1];
    float a0 = 0.f, a1 = 0.f;
    int j = beg;
    for (; j + 8 <= end; j += 8) {
        u32 p0 = X2[(size_t)cols[j + 0] * 64 + lane];
        u32 p1 = X2[(size_t)cols[j + 1] * 64 + lane];
        u32 p2 = X2[(size_t)cols[j + 2] * 64 + lane];
        u32 p3 = X2[(size_t)cols[j + 3] * 64 + lane];
        u32 p4 = X2[(size_t)cols[j + 4] * 64 + lane];
        u32 p5 = X2[(size_t)cols[j + 5] * 64 + lane];
        u32 p6 = X2[(size_t)cols[j + 6] * 64 + lane];
        u32 p7 = X2[(size_t)cols[j + 7] * 64 + lane];
        a0 += bf2f(p0 & 0xffffu) + bf2f(p1 & 0xffffu) + bf2f(p2 & 0xffffu) + bf2f(p3 & 0xffffu)
            + bf2f(p4 & 0xffffu) + bf2f(p5 & 0xffffu) + bf2f(p6 & 0xffffu) + bf2f(p7 & 0xffffu);
        a1 += bf2f(p0 >> 16) + bf2f(p1 >> 16) + bf2f(p2 >> 16) + bf2f(p3 >> 16)
            + bf2f(p4 >> 16) + bf2f(p5 >> 16) + bf2f(p6 >> 16) + bf2f(p7 >> 16);
    }
    for (; j < end; ++j) {
        u32 p = X2[(size_t)cols[j] * 64 + lane];
        a0 += bf2f(p & 0xffffu);
        a1 += bf2f(p >> 16);
    }
    float s = inv_deg[w];
    a0 *= s; a1 *= s;
    u32 px = X2[(size_t)w * 64 + lane];
    float x0 = bf2f(px & 0xffffu), x1 = bf2f(px >> 16);
    int cc = lane >> 4, qq = (lane >> 2) & 3, jj = lane & 3;
    size_t dst = (size_t)(w >> 4) * 1024 + cc * 256 + qq * 64 + (w & 15) * 4 + jj;
    Sp[dst] = (u32)f2bf(a0) | ((u32)f2bf(a1) << 16);
    Dp[dst] = (u32)f2bf(x0 - a0) | ((u32)f2bf(x1 - a1) << 16);
    Xp[dst] = px;
}

// ---------------- fused GEMM + attention combine, fragment-packed operands ----------------
template<int HOUT, bool L1>
__global__ __launch_bounds__(256)
void k_gemm_comb(const u16* __restrict__ Ap0, const u16* __restrict__ Ap1, const u16* __restrict__ Ap2,
                 const u16* __restrict__ Wp,
                 const float* __restrict__ vl, const float* __restrict__ vh, const float* __restrict__ vm,
                 const float* __restrict__ att, int n,
                 u16* __restrict__ feaOut, float* __restrict__ fOut) {
    constexpr int KPG = HOUT / 64;
    constexpr int NTw = 3 * KPG;
    int w = threadIdx.x >> 6, lane = threadIdx.x & 63;
    int ln15 = lane & 15, lq = lane >> 4;
    int m0 = blockIdx.x * 64;

    f32x4 acc[4][NTw];
#pragma unroll
    for (int mt = 0; mt < 4; ++mt)
#pragma unroll
        for (int k = 0; k < NTw; ++k) { f32x4 z = {0.f, 0.f, 0.f, 0.f}; acc[mt][k] = z; }

    for (int c = 0; c < 4; ++c) {
        short8 bfr[NTw];
#pragma unroll
        for (int k = 0; k < NTw; ++k) {
            int g = k / KPG, kk = k % KPG;
            int Tl = w + kk * 4;
            bfr[k] = *(const short8*)(Wp + (size_t)g * (HOUT * 128) + (Tl * 4 + c) * 512 + lane * 8);
        }
#pragma unroll
        for (int mt = 0; mt < 4; ++mt) {
            size_t off = ((size_t)((m0 >> 4) + mt) * 4 + c) * 512 + lane * 8;
            short8 a0 = *(const short8*)(Ap0 + off);
            short8 a1 = *(const short8*)(Ap1 + off);
            short8 a2 = *(const short8*)(Ap2 + off);
#pragma unroll
            for (int k = 0; k < NTw; ++k) {
                int g = k / KPG;
                short8 av = (g == 0) ? a0 : ((g == 1) ? a1 : a2);
                acc[mt][k] = __builtin_amdgcn_mfma_f32_16x16x32_bf16(av, bfr[k], acc[mt][k], 0, 0, 0);
            }
        }
    }

    float vval[NTw];
#pragma unroll
    for (int k = 0; k < NTw; ++k) {
        int g = k / KPG, kk = k % KPG;
        int col = w * 16 + kk * 64 + ln15;
        vval[k] = (g == 0 ? vl : (g == 1 ? vh : vm))[col];
    }

    __shared__ float part[4][3][64];
    __shared__ float wgt[64][3];
#pragma unroll
    for (int mt = 0; mt < 4; ++mt) {
        float pdg[3][4];
#pragma unroll
        for (int g = 0; g < 3; ++g)
#pragma unroll
            for (int r = 0; r < 4; ++r) pdg[g][r] = 0.f;
#pragma unroll
        for (int k = 0; k < NTw; ++k) {
            int g = k / KPG;
#pragma unroll
            for (int r = 0; r < 4; ++r)
                pdg[g][r] += fmaxf(acc[mt][k][r], 0.f) * vval[k];
        }
#pragma unroll
        for (int off = 1; off < 16; off <<= 1)
#pragma unroll
            for (int g = 0; g < 3; ++g)
#pragma unroll
                for (int r = 0; r < 4; ++r)
                    pdg[g][r] += __shfl_xor(pdg[g][r], off);
        if (ln15 == 0) {
#pragma unroll
            for (int g = 0; g < 3; ++g)
#pragma unroll
                for (int r = 0; r < 4; ++r)
                    part[w][g][mt * 16 + lq * 4 + r] = pdg[g][r];
        }
    }
    __syncthreads();
    if (threadIdx.x < 64) {
        int row = threadIdx.x;
        float d0 = part[0][0][row] + part[1][0][row] + part[2][0][row] + part[3][0][row];
        float d1 = part[0][1][row] + part[1][1][row] + part[2][1][row] + part[3][1][row];
        float d2 = part[0][2][row] + part[1][2][row] + part[2][2][row] + part[3][2][row];
        float s0 = 1.f / (1.f + __expf(-d0));
        float s1 = 1.f / (1.f + __expf(-d1));
        float s2 = 1.f / (1.f + __expf(-d2));
        float a0 = (s0 * att[0] + s1 * att[3] + s2 * att[6]) * (1.f / 3.f);
        float a1 = (s0 * att[1] + s1 * att[4] + s2 * att[7]) * (1.f / 3.f);
        float a2 = (s0 * att[2] + s1 * att[5] + s2 * att[8]) * (1.f / 3.f);
        float mx = fmaxf(a0, fmaxf(a1, a2));
        float e0 = __expf(a0 - mx), e1 = __expf(a1 - mx), e2 = __expf(a2 - mx);
        float inv = 3.f / (e0 + e1 + e2);
        wgt[row][0] = e0 * inv;
        wgt[row][1] = e1 * inv;
        wgt[row][2] = e2 * inv;
    }
    __syncthreads();

#pragma unroll
    for (int mt = 0; mt < 4; ++mt)
#pragma unroll
        for (int kk = 0; kk < KPG; ++kk)
#pragma unroll
            for (int r = 0; r < 4; ++r) {
                int row_local = mt * 16 + lq * 4 + r;
                int row = m0 + row_local;
                if (row < n) {
                    int col = w * 16 + kk * 64 + ln15;
                    float w0 = wgt[row_local][0], w1 = wgt[row_local][1], w2 = wgt[row_local][2];
                    float ol = fmaxf(acc[mt][0 * KPG + kk][r], 0.f);
                    float oh = fmaxf(acc[mt][1 * KPG + kk][r], 0.f);
                    float om = fmaxf(acc[mt][2 * KPG + kk][r], 0.f);
                    float val = w0 * ol + w1 * oh + w2 * om;
                    if (L1)
                        feaOut[(size_t)row * HOUT + col] = f2bf(fmaxf(val, 0.f));
                    else
                        fOut[(size_t)row * HOUT + col] = val;
                }
            }
}

extern "C" void kernel_launch(void* const* d_in, const int* in_sizes, int n_in,
                              void* d_out, int out_size, void* d_ws, size_t ws_size,
                              hipStream_t stream) {
    const int F = 128;
    int n = in_sizes[0] / F;
    int e = in_sizes[1] / 2;
    int n64 = (n + 63) & ~63;
    int nbuck = (n + (1 << BSHIFT) - 1) >> BSHIFT;
    const float* x = (const float*)d_in[0];
    const int* ei = (const int*)d_in[1];
    const int* erow = ei;
    const int* ecol = ei + e;
    const float *Wl1 = (const float*)d_in[2], *Wh1 = (const float*)d_in[3], *Wm1 = (const float*)d_in[4];
    const float *vl1 = (const float*)d_in[5], *vh1 = (const float*)d_in[6], *vm1 = (const float*)d_in[7];
    const float* att1 = (const float*)d_in[8];
    const float *Wl2 = (const float*)d_in[9], *Wh2 = (const float*)d_in[10], *Wm2 = (const float*)d_in[11];
    const float *vl2 = (const float*)d_in[12], *vh2 = (const float*)d_in[13], *vm2 = (const float*)d_in[14];
    const float* att2 = (const float*)d_in[15];
    float* out = (float*)d_out;

    char* ws = (char*)d_ws;
    size_t off = 0;
    auto alloc = [&](size_t b) -> void* {
        void* p = ws + off;
        off = (off + b + 255) & ~(size_t)255;
        return p;
    };
    int* deg = (int*)alloc((size_t)n * 4);
    int* row_ptr = (int*)alloc((size_t)(n + 1) * 4);
    float* inv_deg = (float*)alloc((size_t)n * 4);
    int* bsum = (int*)alloc(1024);
    int* boff = (int*)alloc(1024);
    int* gcursor = (int*)alloc(MAXBUCK * 4);
    u64* bedge = (u64*)alloc((size_t)e * 8);
    int* cols = (int*)alloc((size_t)e * 4);
    u32* Sp = (u32*)alloc((size_t)n64 * 64 * 4);
    u32* Dp = (u32*)alloc((size_t)n64 * 64 * 4);
    u32* Xp = (u32*)alloc((size_t)n64 * 64 * 4);
    u32* Fp = (u32*)alloc((size_t)n64 * 64 * 4);
    u16* Xb = (u16*)alloc((size_t)n * 128 * 2);
    u16* fea = (u16*)alloc((size_t)n * 128 * 2);
    u16* Wp1 = (u16*)alloc((size_t)3 * 128 * 128 * 2);
    u16* Wp2 = (u16*)alloc((size_t)3 * 64 * 128 * 2);
    (void)ws_size; (void)n_in; (void)out_size;

    const int tb = 256;
    k_cast<<<2048, 256, 0, stream>>>((const float4*)x, (u32*)Xb, (long)n * 32);
    k_prepW<<<dim3(16, 6), 256, 0, stream>>>(Wl1, Wh1, Wm1, Wl2, Wh2, Wm2, Wp1, Wp2);

    hipMemsetAsync(deg, 0, (size_t)n * 4, stream);
    k_deg<<<(e + tb - 1) / tb, tb, 0, stream>>>(erow, e, deg);
    int nb = (n + 1023) / 1024;
    k_scan_a<<<nb, 256, 0, stream>>>(deg, n, bsum);
    k_scan_b<<<1, 256, 0, stream>>>(bsum, nb, boff);
    k_scan_c<<<nb, 256, 0, stream>>>(deg, n, boff, row_ptr, inv_deg);

    k_ginit<<<(nbuck + 255) / 256, 256, 0, stream>>>(row_ptr, n, nbuck, gcursor);
    k_bscatter<<<256, 256, 0, stream>>>(erow, ecol, e, nbuck, gcursor, bedge);
    k_bfill<<<nbuck, 256, 0, stream>>>(bedge, row_ptr, n, cols);

    int wb = (n + 3) / 4;
    int gb = n64 / 64;

    // layer 1
    k_spmm<<<wb, 256, 0, stream>>>((const u32*)Xb, row_ptr, cols, inv_deg, Sp, Dp, Xp, n);
    k_gemm_comb<128, true><<<gb, 256, 0, stream>>>((const u16*)Sp, (const u16*)Dp, (const u16*)Xp,
                                                   Wp1, vl1, vh1, vm1, att1, n, fea, nullptr);

    // layer 2
    k_spmm<<<wb, 256, 0, stream>>>((const u32*)fea, row_ptr, cols, inv_deg, Sp, Dp, Fp, n);
    k_gemm_comb<64, false><<<gb, 256, 0, stream>>>((const u16*)Sp, (const u16*)Dp, (const u16*)Fp,
                                                   Wp2, vl2, vh2, vm2, att2, n, nullptr, out);
}

// Round 8
// 527.571 us; speedup vs baseline: 1.0365x; 1.0365x over previous
//
#include <hip/hip_runtime.h>

typedef unsigned short u16;
typedef unsigned int u32;
typedef unsigned long long u64;
typedef __attribute__((ext_vector_type(8))) short short8;
typedef __attribute__((ext_vector_type(4))) float f32x4;

#define BSHIFT 8               // 256 rows per bucket
#define MAXBUCK 512

__device__ __forceinline__ float bf2f(u32 u) {
    union { u32 i; float f; } v; v.i = u << 16; return v.f;
}
__device__ __forceinline__ u16 f2bf(float f) {
    union { float f; u32 i; } v; v.f = f;
    u32 u = (v.i + 0x7fffu + ((v.i >> 16) & 1u)) >> 16;
    return (u16)u;
}

// ---------------- fused: cast x -> bf16 row-major  +  pack weights (with -Wh copy) ----------------
// W pack layout per layer: 4 matrices [Wl, -Wh, Wh, Wm], each MFMA-B-fragment packed:
// u16 idx = (T*4 + c)*512 + lane*8 + j ; col = T*16 + (lane&15), k = c*32 + (lane>>4)*8 + j.
#define CASTBLK 2048
__global__ void k_prep(const float4* __restrict__ X, u32* __restrict__ Xb, long total4,
                       const float* __restrict__ Wl1, const float* __restrict__ Wh1,
                       const float* __restrict__ Wm1, const float* __restrict__ Wl2,
                       const float* __restrict__ Wh2, const float* __restrict__ Wm2,
                       u16* __restrict__ Wp1, u16* __restrict__ Wp2) {
    if (blockIdx.x < CASTBLK) {
        long i = (long)blockIdx.x * blockDim.x + threadIdx.x;
        long stride = (long)CASTBLK * blockDim.x;
        for (; i < total4; i += stride) {
            float4 p = X[i];
            Xb[i * 2 + 0] = (u32)f2bf(p.x) | ((u32)f2bf(p.y) << 16);
            Xb[i * 2 + 1] = (u32)f2bf(p.z) | ((u32)f2bf(p.w) << 16);
        }
        return;
    }
    int tid = (blockIdx.x - CASTBLK) * blockDim.x + threadIdx.x;
    int nthr = 16 * blockDim.x;
    for (int m = 0; m < 8; ++m) {
        int layer = m >> 2;          // 0: L1, 1: L2
        int slot = m & 3;            // 0 Wl, 1 -Wh, 2 Wh, 3 Wm
        int Hout = layer ? 64 : 128;
        const float* W = layer ? (slot == 0 ? Wl2 : (slot == 3 ? Wm2 : Wh2))
                               : (slot == 0 ? Wl1 : (slot == 3 ? Wm1 : Wh1));
        float sgn = (slot == 1) ? -1.f : 1.f;
        u16* dst = (layer ? Wp2 : Wp1) + slot * Hout * 128;
        int total = 128 * Hout;
        for (int i = tid; i < total; i += nthr) {
            int T = i / 2048;
            int c = (i / 512) & 3;
            int lane = (i / 8) & 63;
            int j = i & 7;
            int col = T * 16 + (lane & 15);
            int k = c * 32 + (lane >> 4) * 8 + j;
            dst[i] = f2bf(sgn * W[k * Hout + col]);
        }
    }
}

// ---------------- CSR build: degree + row_ptr scan ----------------
__global__ void k_deg(const int* __restrict__ erow, int e, int* __restrict__ deg) {
    int i = blockIdx.x * blockDim.x + threadIdx.x;
    if (i < e) atomicAdd(&deg[erow[i]], 1);
}

__global__ void k_scan_a(const int* __restrict__ deg, int n, int* __restrict__ bsum) {
    __shared__ int lds[256];
    int b = blockIdx.x, t = threadIdx.x;
    int base = b * 1024;
    int s = 0;
    for (int i = t; i < 1024; i += 256) { int idx = base + i; if (idx < n) s += deg[idx]; }
    lds[t] = s; __syncthreads();
    for (int off = 128; off > 0; off >>= 1) { if (t < off) lds[t] += lds[t + off]; __syncthreads(); }
    if (t == 0) bsum[b] = lds[0];
}

__global__ void k_scan_b(const int* __restrict__ bsum, int nb, int* __restrict__ boff) {
    __shared__ int lds[256];
    int t = threadIdx.x;
    int v = (t < nb) ? bsum[t] : 0;
    lds[t] = v; __syncthreads();
    for (int off = 1; off < 256; off <<= 1) {
        int x = (t >= off) ? lds[t - off] : 0;
        __syncthreads();
        lds[t] += x;
        __syncthreads();
    }
    if (t < nb) boff[t] = lds[t] - v;
}

// also initializes gcursor at bucket boundaries (row % 256 == 0)
__global__ void k_scan_c(const int* __restrict__ deg, int n, const int* __restrict__ boff,
                         int* __restrict__ row_ptr, float* __restrict__ inv_deg,
                         int* __restrict__ gcursor) {
    __shared__ int lds[256];
    int b = blockIdx.x, t = threadIdx.x;
    int base = b * 1024 + t * 4;
    int v0 = 0, v1 = 0, v2 = 0, v3 = 0;
    if (base + 0 < n) v0 = deg[base + 0];
    if (base + 1 < n) v1 = deg[base + 1];
    if (base + 2 < n) v2 = deg[base + 2];
    if (base + 3 < n) v3 = deg[base + 3];
    int s = v0 + v1 + v2 + v3;
    lds[t] = s; __syncthreads();
    for (int off = 1; off < 256; off <<= 1) {
        int x = (t >= off) ? lds[t - off] : 0;
        __syncthreads();
        lds[t] += x;
        __syncthreads();
    }
    int run = boff[b] + lds[t] - s;
    if (base + 0 < n) { row_ptr[base + 0] = run; if (((base + 0) & 255) == 0) gcursor[(base + 0) >> BSHIFT] = run; inv_deg[base + 0] = v0 > 0 ? 1.f / v0 : 0.f; run += v0; }
    if (base + 1 < n) { row_ptr[base + 1] = run; inv_deg[base + 1] = v1 > 0 ? 1.f / v1 : 0.f; run += v1; }
    if (base + 2 < n) { row_ptr[base + 2] = run; inv_deg[base + 2] = v2 > 0 ? 1.f / v2 : 0.f; run += v2; }
    if (base + 3 < n) { row_ptr[base + 3] = run; inv_deg[base + 3] = v3 > 0 ? 1.f / v3 : 0.f; run += v3; }
    if (b == gridDim.x - 1 && t == 255) row_ptr[n] = run;
}

// ---------------- bucketed edge sort; bedge packed u32 = (col<<8) | (row & 255) ----------------
__global__ void k_bscatter(const int* __restrict__ erow, const int* __restrict__ ecol, int e,
                           int nbuck, int* __restrict__ gcursor, u32* __restrict__ bedge) {
    __shared__ int hist[MAXBUCK];
    __shared__ int base[MAXBUCK];
    for (int t = threadIdx.x; t < nbuck; t += blockDim.x) hist[t] = 0;
    __syncthreads();
    int chunk = (e + gridDim.x - 1) / gridDim.x;
    int lo = blockIdx.x * chunk, hi = min(e, lo + chunk);
    for (int i = lo + threadIdx.x; i < hi; i += blockDim.x)
        atomicAdd(&hist[erow[i] >> BSHIFT], 1);
    __syncthreads();
    for (int t = threadIdx.x; t < nbuck; t += blockDim.x) {
        int c = hist[t];
        base[t] = c ? atomicAdd(&gcursor[t], c) : 0;
        hist[t] = 0;
    }
    __syncthreads();
    for (int i = lo + threadIdx.x; i < hi; i += blockDim.x) {
        int r = erow[i];
        int bk = r >> BSHIFT;
        int pos = base[bk] + atomicAdd(&hist[bk], 1);
        bedge[pos] = ((u32)ecol[i] << 8) | (u32)(r & 255);
    }
}

__global__ void k_bfill(const u32* __restrict__ bedge, const int* __restrict__ row_ptr, int n,
                        int* __restrict__ cols) {
    __shared__ int cur[1 << BSHIFT];
    int b = blockIdx.x;
    for (int t = threadIdx.x; t < (1 << BSHIFT); t += blockDim.x) cur[t] = 0;
    __syncthreads();
    int rbase = b << BSHIFT;
    int rend = min(n, rbase + (1 << BSHIFT));
    int lo = row_ptr[rbase], hi = row_ptr[rend];
    for (int i = lo + threadIdx.x; i < hi; i += blockDim.x) {
        u32 v = bedge[i];
        int rl = (int)(v & 255u);
        int c = (int)(v >> 8);
        int p = row_ptr[rbase + rl] + atomicAdd(&cur[rl], 1);
        cols[p] = c;
    }
}

// ---------------- SpMM: bf16 X row-major in; A-fragment-packed S (=adj@X scaled) and X out ----------------
__global__ void k_spmm(const u32* __restrict__ X2, const int* __restrict__ row_ptr,
                       const int* __restrict__ cols, const float* __restrict__ inv_deg,
                       u32* __restrict__ Sp, u32* __restrict__ Xp, int n) {
    int w = (int)((blockIdx.x * blockDim.x + threadIdx.x) >> 6);
    if (w >= n) return;
    int lane = threadIdx.x & 63;
    int beg = row_ptr[w], end = row_ptr[w + 1];
    float a0 = 0.f, a1 = 0.f;
    for (int j0 = beg; j0 < end; j0 += 64) {
        int cnt = end - j0; if (cnt > 64) cnt = 64;
        int myc = (lane < cnt) ? cols[j0 + lane] : 0;
        int j = 0;
        for (; j + 4 <= cnt; j += 4) {
            int c0 = __shfl(myc, j + 0);
            int c1 = __shfl(myc, j + 1);
            int c2 = __shfl(myc, j + 2);
            int c3 = __shfl(myc, j + 3);
            u32 p0 = X2[(size_t)c0 * 64 + lane];
            u32 p1 = X2[(size_t)c1 * 64 + lane];
            u32 p2 = X2[(size_t)c2 * 64 + lane];
            u32 p3 = X2[(size_t)c3 * 64 + lane];
            a0 += bf2f(p0 & 0xffffu) + bf2f(p1 & 0xffffu) + bf2f(p2 & 0xffffu) + bf2f(p3 & 0xffffu);
            a1 += bf2f(p0 >> 16) + bf2f(p1 >> 16) + bf2f(p2 >> 16) + bf2f(p3 >> 16);
        }
        for (; j < cnt; ++j) {
            int c = __shfl(myc, j);
            u32 p = X2[(size_t)c * 64 + lane];
            a0 += bf2f(p & 0xffffu);
            a1 += bf2f(p >> 16);
        }
    }
    float s = inv_deg[w];
    a0 *= s; a1 *= s;
    u32 px = X2[(size_t)w * 64 + lane];
    int cc = lane >> 4, qq = (lane >> 2) & 3, jj = lane & 3;
    size_t dst = (size_t)(w >> 4) * 1024 + cc * 256 + qq * 64 + (w & 15) * 4 + jj;
    Sp[dst] = (u32)f2bf(a0) | ((u32)f2bf(a1) << 16);
    Xp[dst] = px;
}

// ---------------- fused GEMM + attention combine; A = {S, X}; W = [Wl, -Wh, Wh, Wm] ----------------
// out_low = S@Wl, out_high = S@(-Wh) + X@Wh, out_mlp = X@Wm.
template<int HOUT, int MT, bool L1>
__global__ __launch_bounds__(256)
void k_gemm_comb(const u16* __restrict__ Sp, const u16* __restrict__ Xp,
                 const u16* __restrict__ Wp,
                 const float* __restrict__ vl, const float* __restrict__ vh, const float* __restrict__ vm,
                 const float* __restrict__ att, int n,
                 u16* __restrict__ feaOut, float* __restrict__ fOut) {
    constexpr int KPG = HOUT / 64;
    constexpr int NTw = 3 * KPG;
    constexpr int ROWS = MT * 16;
    int w = threadIdx.x >> 6, lane = threadIdx.x & 63;
    int ln15 = lane & 15, lq = lane >> 4;
    int m0 = blockIdx.x * ROWS;

    f32x4 acc[MT][NTw];
#pragma unroll
    for (int mt = 0; mt < MT; ++mt)
#pragma unroll
        for (int k = 0; k < NTw; ++k) { f32x4 z = {0.f, 0.f, 0.f, 0.f}; acc[mt][k] = z; }

    for (int c = 0; c < 4; ++c) {
        short8 bl[KPG], bhn[KPG], bhp[KPG], bm[KPG];
#pragma unroll
        for (int kk = 0; kk < KPG; ++kk) {
            int Tl = w + kk * 4;
            size_t fo = (size_t)(Tl * 4 + c) * 512 + lane * 8;
            bl[kk]  = *(const short8*)(Wp + (size_t)0 * (HOUT * 128) + fo);
            bhn[kk] = *(const short8*)(Wp + (size_t)1 * (HOUT * 128) + fo);
            bhp[kk] = *(const short8*)(Wp + (size_t)2 * (HOUT * 128) + fo);
            bm[kk]  = *(const short8*)(Wp + (size_t)3 * (HOUT * 128) + fo);
        }
#pragma unroll
        for (int mt = 0; mt < MT; ++mt) {
            size_t off = ((size_t)((m0 >> 4) + mt) * 4 + c) * 512 + lane * 8;
            short8 as = *(const short8*)(Sp + off);
            short8 ax = *(const short8*)(Xp + off);
#pragma unroll
            for (int kk = 0; kk < KPG; ++kk) {
                acc[mt][0 * KPG + kk] = __builtin_amdgcn_mfma_f32_16x16x32_bf16(as, bl[kk], acc[mt][0 * KPG + kk], 0, 0, 0);
                acc[mt][1 * KPG + kk] = __builtin_amdgcn_mfma_f32_16x16x32_bf16(as, bhn[kk], acc[mt][1 * KPG + kk], 0, 0, 0);
                acc[mt][1 * KPG + kk] = __builtin_amdgcn_mfma_f32_16x16x32_bf16(ax, bhp[kk], acc[mt][1 * KPG + kk], 0, 0, 0);
                acc[mt][2 * KPG + kk] = __builtin_amdgcn_mfma_f32_16x16x32_bf16(ax, bm[kk], acc[mt][2 * KPG + kk], 0, 0, 0);
            }
        }
    }

    float vval[NTw];
#pragma unroll
    for (int k = 0; k < NTw; ++k) {
        int g = k / KPG, kk = k % KPG;
        int col = w * 16 + kk * 64 + ln15;
        vval[k] = (g == 0 ? vl : (g == 1 ? vh : vm))[col];
    }

    __shared__ float part[4][3][ROWS];
    __shared__ float wgt[ROWS][3];
#pragma unroll
    for (int mt = 0; mt < MT; ++mt) {
        float pdg[3][4];
#pragma unroll
        for (int g = 0; g < 3; ++g)
#pragma unroll
            for (int r = 0; r < 4; ++r) pdg[g][r] = 0.f;
#pragma unroll
        for (int k = 0; k < NTw; ++k) {
            int g = k / KPG;
#pragma unroll
            for (int r = 0; r < 4; ++r)
                pdg[g][r] += fmaxf(acc[mt][k][r], 0.f) * vval[k];
        }
#pragma unroll
        for (int off = 1; off < 16; off <<= 1)
#pragma unroll
            for (int g = 0; g < 3; ++g)
#pragma unroll
                for (int r = 0; r < 4; ++r)
                    pdg[g][r] += __shfl_xor(pdg[g][r], off);
        if (ln15 == 0) {
#pragma unroll
            for (int g = 0; g < 3; ++g)
#pragma unroll
                for (int r = 0; r < 4; ++r)
                    part[w][g][mt * 16 + lq * 4 + r] = pdg[g][r];
        }
    }
    __syncthreads();
    if (threadIdx.x < ROWS) {
        int row = threadIdx.x;
        float d0 = part[0][0][row] + part[1][0][row] + part[2][0][row] + part[3][0][row];
        float d1 = part[0][1][row] + part[1][1][row] + part[2][1][row] + part[3][1][row];
        float d2 = part[0][2][row] + part[1][2][row] + part[2][2][row] + part[3][2][row];
        float s0 = 1.f / (1.f + __expf(-d0));
        float s1 = 1.f / (1.f + __expf(-d1));
        float s2 = 1.f / (1.f + __expf(-d2));
        float a0 = (s0 * att[0] + s1 * att[3] + s2 * att[6]) * (1.f / 3.f);
        float a1 = (s0 * att[1] + s1 * att[4] + s2 * att[7]) * (1.f / 3.f);
        float a2 = (s0 * att[2] + s1 * att[5] + s2 * att[8]) * (1.f / 3.f);
        float mx = fmaxf(a0, fmaxf(a1, a2));
        float e0 = __expf(a0 - mx), e1 = __expf(a1 - mx), e2 = __expf(a2 - mx);
        float inv = 3.f / (e0 + e1 + e2);
        wgt[row][0] = e0 * inv;
        wgt[row][1] = e1 * inv;
        wgt[row][2] = e2 * inv;
    }
    __syncthreads();

#pragma unroll
    for (int mt = 0; mt < MT; ++mt)
#pragma unroll
        for (int kk = 0; kk < KPG; ++kk)
#pragma unroll
            for (int r = 0; r < 4; ++r) {
                int row_local = mt * 16 + lq * 4 + r;
                int row = m0 + row_local;
                if (row < n) {
                    int col = w * 16 + kk * 64 + ln15;
                    float w0 = wgt[row_local][0], w1 = wgt[row_local][1], w2 = wgt[row_local][2];
                    float ol = fmaxf(acc[mt][0 * KPG + kk][r], 0.f);
                    float oh = fmaxf(acc[mt][1 * KPG + kk][r], 0.f);
                    float om = fmaxf(acc[mt][2 * KPG + kk][r], 0.f);
                    float val = w0 * ol + w1 * oh + w2 * om;
                    if (L1)
                        feaOut[(size_t)row * HOUT + col] = f2bf(fmaxf(val, 0.f));
                    else
                        fOut[(size_t)row * HOUT + col] = val;
                }
            }
}

extern "C" void kernel_launch(void* const* d_in, const int* in_sizes, int n_in,
                              void* d_out, int out_size, void* d_ws, size_t ws_size,
                              hipStream_t stream) {
    const int F = 128;
    int n = in_sizes[0] / F;
    int e = in_sizes[1] / 2;
    int n128 = (n + 127) & ~127;
    int nbuck = (n + (1 << BSHIFT) - 1) >> BSHIFT;
    const float* x = (const float*)d_in[0];
    const int* ei = (const int*)d_in[1];
    const int* erow = ei;
    const int* ecol = ei + e;
    const float *Wl1 = (const float*)d_in[2], *Wh1 = (const float*)d_in[3], *Wm1 = (const float*)d_in[4];
    const float *vl1 = (const float*)d_in[5], *vh1 = (const float*)d_in[6], *vm1 = (const float*)d_in[7];
    const float* att1 = (const float*)d_in[8];
    const float *Wl2 = (const float*)d_in[9], *Wh2 = (const float*)d_in[10], *Wm2 = (const float*)d_in[11];
    const float *vl2 = (const float*)d_in[12], *vh2 = (const float*)d_in[13], *vm2 = (const float*)d_in[14];
    const float* att2 = (const float*)d_in[15];
    float* out = (float*)d_out;

    char* ws = (char*)d_ws;
    size_t off = 0;
    auto alloc = [&](size_t b) -> void* {
        void* p = ws + off;
        off = (off + b + 255) & ~(size_t)255;
        return p;
    };
    int* deg = (int*)alloc((size_t)n * 4);
    int* row_ptr = (int*)alloc((size_t)(n + 1) * 4);
    float* inv_deg = (float*)alloc((size_t)n * 4);
    int* bsum = (int*)alloc(1024);
    int* boff = (int*)alloc(1024);
    int* gcursor = (int*)alloc(MAXBUCK * 4);
    u32* bedge = (u32*)alloc((size_t)e * 4);
    int* cols = (int*)alloc((size_t)e * 4);
    u32* Sp = (u32*)alloc((size_t)n128 * 64 * 4);
    u32* Xp = (u32*)alloc((size_t)n128 * 64 * 4);
    u32* Fp = (u32*)alloc((size_t)n128 * 64 * 4);
    u16* Xb = (u16*)alloc((size_t)n * 128 * 2);
    u16* fea = (u16*)alloc((size_t)n * 128 * 2);
    u16* Wp1 = (u16*)alloc((size_t)4 * 128 * 128 * 2);
    u16* Wp2 = (u16*)alloc((size_t)4 * 64 * 128 * 2);
    (void)ws_size; (void)n_in; (void)out_size;

    const int tb = 256;
    k_prep<<<CASTBLK + 16, 256, 0, stream>>>((const float4*)x, (u32*)Xb, (long)n * 32,
                                             Wl1, Wh1, Wm1, Wl2, Wh2, Wm2, Wp1, Wp2);

    hipMemsetAsync(deg, 0, (size_t)n * 4, stream);
    k_deg<<<(e + tb - 1) / tb, tb, 0, stream>>>(erow, e, deg);
    int nb = (n + 1023) / 1024;
    k_scan_a<<<nb, 256, 0, stream>>>(deg, n, bsum);
    k_scan_b<<<1, 256, 0, stream>>>(bsum, nb, boff);
    k_scan_c<<<nb, 256, 0, stream>>>(deg, n, boff, row_ptr, inv_deg, gcursor);

    k_bscatter<<<256, 256, 0, stream>>>(erow, ecol, e, nbuck, gcursor, bedge);
    k_bfill<<<nbuck, 256, 0, stream>>>(bedge, row_ptr, n, cols);

    int wb = (n + 3) / 4;

    // layer 1: 64 rows/block
    k_spmm<<<wb, 256, 0, stream>>>((const u32*)Xb, row_ptr, cols, inv_deg, Sp, Xp, n);
    k_gemm_comb<128, 4, true><<<(n + 63) / 64, 256, 0, stream>>>((const u16*)Sp, (const u16*)Xp,
                                                                 Wp1, vl1, vh1, vm1, att1, n, fea, nullptr);

    // layer 2: 128 rows/block
    k_spmm<<<wb, 256, 0, stream>>>((const u32*)fea, row_ptr, cols, inv_deg, Sp, Fp, n);
    k_gemm_comb<64, 8, false><<<n128 / 128, 256, 0, stream>>>((const u16*)Sp, (const u16*)Fp,
                                                              Wp2, vl2, vh2, vm2, att2, n, nullptr, out);
}

// Round 9
// 486.218 us; speedup vs baseline: 1.1247x; 1.0851x over previous
//
#include <hip/hip_runtime.h>

typedef unsigned short u16;
typedef unsigned int u32;
typedef unsigned long long u64;
typedef __attribute__((ext_vector_type(8))) short short8;
typedef __attribute__((ext_vector_type(4))) float f32x4;

#define BSHIFT 8               // 256 rows per bucket
#define MAXBUCK 512

__device__ __forceinline__ float bf2f(u32 u) {
    union { u32 i; float f; } v; v.i = u << 16; return v.f;
}
__device__ __forceinline__ u16 f2bf(float f) {
    union { float f; u32 i; } v; v.f = f;
    u32 u = (v.i + 0x7fffu + ((v.i >> 16) & 1u)) >> 16;
    return (u16)u;
}

// ---------------- fused: cast x -> bf16 row-major  +  pack weights (with -Wh copy) ----------------
// W pack layout per layer: 4 matrices [Wl, -Wh, Wh, Wm], each MFMA-B-fragment packed:
// u16 idx = (T*4 + c)*512 + lane*8 + j ; col = T*16 + (lane&15), k = c*32 + (lane>>4)*8 + j.
#define CASTBLK 2048
__global__ void k_prep(const float4* __restrict__ X, u32* __restrict__ Xb, long total4,
                       const float* __restrict__ Wl1, const float* __restrict__ Wh1,
                       const float* __restrict__ Wm1, const float* __restrict__ Wl2,
                       const float* __restrict__ Wh2, const float* __restrict__ Wm2,
                       u16* __restrict__ Wp1, u16* __restrict__ Wp2) {
    if (blockIdx.x < CASTBLK) {
        long i = (long)blockIdx.x * blockDim.x + threadIdx.x;
        long stride = (long)CASTBLK * blockDim.x;
        for (; i < total4; i += stride) {
            float4 p = X[i];
            Xb[i * 2 + 0] = (u32)f2bf(p.x) | ((u32)f2bf(p.y) << 16);
            Xb[i * 2 + 1] = (u32)f2bf(p.z) | ((u32)f2bf(p.w) << 16);
        }
        return;
    }
    int tid = (blockIdx.x - CASTBLK) * blockDim.x + threadIdx.x;
    int nthr = 16 * blockDim.x;
    for (int m = 0; m < 8; ++m) {
        int layer = m >> 2;          // 0: L1, 1: L2
        int slot = m & 3;            // 0 Wl, 1 -Wh, 2 Wh, 3 Wm
        int Hout = layer ? 64 : 128;
        const float* W = layer ? (slot == 0 ? Wl2 : (slot == 3 ? Wm2 : Wh2))
                               : (slot == 0 ? Wl1 : (slot == 3 ? Wm1 : Wh1));
        float sgn = (slot == 1) ? -1.f : 1.f;
        u16* dst = (layer ? Wp2 : Wp1) + slot * Hout * 128;
        int total = 128 * Hout;
        for (int i = tid; i < total; i += nthr) {
            int T = i / 2048;
            int c = (i / 512) & 3;
            int lane = (i / 8) & 63;
            int j = i & 7;
            int col = T * 16 + (lane & 15);
            int k = c * 32 + (lane >> 4) * 8 + j;
            dst[i] = f2bf(sgn * W[k * Hout + col]);
        }
    }
}

// ---------------- CSR build: degree + row_ptr scan ----------------
__global__ void k_deg(const int* __restrict__ erow, int e, int* __restrict__ deg) {
    int i = blockIdx.x * blockDim.x + threadIdx.x;
    if (i < e) atomicAdd(&deg[erow[i]], 1);
}

__global__ void k_scan_a(const int* __restrict__ deg, int n, int* __restrict__ bsum) {
    __shared__ int lds[256];
    int b = blockIdx.x, t = threadIdx.x;
    int base = b * 1024;
    int s = 0;
    for (int i = t; i < 1024; i += 256) { int idx = base + i; if (idx < n) s += deg[idx]; }
    lds[t] = s; __syncthreads();
    for (int off = 128; off > 0; off >>= 1) { if (t < off) lds[t] += lds[t + off]; __syncthreads(); }
    if (t == 0) bsum[b] = lds[0];
}

__global__ void k_scan_b(const int* __restrict__ bsum, int nb, int* __restrict__ boff) {
    __shared__ int lds[256];
    int t = threadIdx.x;
    int v = (t < nb) ? bsum[t] : 0;
    lds[t] = v; __syncthreads();
    for (int off = 1; off < 256; off <<= 1) {
        int x = (t >= off) ? lds[t - off] : 0;
        __syncthreads();
        lds[t] += x;
        __syncthreads();
    }
    if (t < nb) boff[t] = lds[t] - v;
}

// also initializes gcursor at bucket boundaries (row % 256 == 0)
__global__ void k_scan_c(const int* __restrict__ deg, int n, const int* __restrict__ boff,
                         int* __restrict__ row_ptr, float* __restrict__ inv_deg,
                         int* __restrict__ gcursor) {
    __shared__ int lds[256];
    int b = blockIdx.x, t = threadIdx.x;
    int base = b * 1024 + t * 4;
    int v0 = 0, v1 = 0, v2 = 0, v3 = 0;
    if (base + 0 < n) v0 = deg[base + 0];
    if (base + 1 < n) v1 = deg[base + 1];
    if (base + 2 < n) v2 = deg[base + 2];
    if (base + 3 < n) v3 = deg[base + 3];
    int s = v0 + v1 + v2 + v3;
    lds[t] = s; __syncthreads();
    for (int off = 1; off < 256; off <<= 1) {
        int x = (t >= off) ? lds[t - off] : 0;
        __syncthreads();
        lds[t] += x;
        __syncthreads();
    }
    int run = boff[b] + lds[t] - s;
    if (base + 0 < n) { row_ptr[base + 0] = run; if (((base + 0) & 255) == 0) gcursor[(base + 0) >> BSHIFT] = run; inv_deg[base + 0] = v0 > 0 ? 1.f / v0 : 0.f; run += v0; }
    if (base + 1 < n) { row_ptr[base + 1] = run; inv_deg[base + 1] = v1 > 0 ? 1.f / v1 : 0.f; run += v1; }
    if (base + 2 < n) { row_ptr[base + 2] = run; inv_deg[base + 2] = v2 > 0 ? 1.f / v2 : 0.f; run += v2; }
    if (base + 3 < n) { row_ptr[base + 3] = run; inv_deg[base + 3] = v3 > 0 ? 1.f / v3 : 0.f; run += v3; }
    if (b == gridDim.x - 1 && t == 255) row_ptr[n] = run;
}

// ---------------- bucketed edge sort; bedge packed u32 = (col<<8) | (row & 255) ----------------
__global__ void k_bscatter(const int* __restrict__ erow, const int* __restrict__ ecol, int e,
                           int nbuck, int* __restrict__ gcursor, u32* __restrict__ bedge) {
    __shared__ int hist[MAXBUCK];
    __shared__ int base[MAXBUCK];
    for (int t = threadIdx.x; t < nbuck; t += blockDim.x) hist[t] = 0;
    __syncthreads();
    int chunk = (e + gridDim.x - 1) / gridDim.x;
    int lo = blockIdx.x * chunk, hi = min(e, lo + chunk);
    for (int i = lo + threadIdx.x; i < hi; i += blockDim.x)
        atomicAdd(&hist[erow[i] >> BSHIFT], 1);
    __syncthreads();
    for (int t = threadIdx.x; t < nbuck; t += blockDim.x) {
        int c = hist[t];
        base[t] = c ? atomicAdd(&gcursor[t], c) : 0;
        hist[t] = 0;
    }
    __syncthreads();
    for (int i = lo + threadIdx.x; i < hi; i += blockDim.x) {
        int r = erow[i];
        int bk = r >> BSHIFT;
        int pos = base[bk] + atomicAdd(&hist[bk], 1);
        bedge[pos] = ((u32)ecol[i] << 8) | (u32)(r & 255);
    }
}

__global__ void k_bfill(const u32* __restrict__ bedge, const int* __restrict__ row_ptr, int n,
                        int* __restrict__ cols) {
    __shared__ int cur[1 << BSHIFT];
    int b = blockIdx.x;
    for (int t = threadIdx.x; t < (1 << BSHIFT); t += blockDim.x) cur[t] = 0;
    __syncthreads();
    int rbase = b << BSHIFT;
    int rend = min(n, rbase + (1 << BSHIFT));
    int lo = row_ptr[rbase], hi = row_ptr[rend];
    for (int i = lo + threadIdx.x; i < hi; i += blockDim.x) {
        u32 v = bedge[i];
        int rl = (int)(v & 255u);
        int c = (int)(v >> 8);
        int p = row_ptr[rbase + rl] + atomicAdd(&cur[rl], 1);
        cols[p] = c;
    }
}

// ---------------- SpMM: bf16 X row-major in; A-fragment-packed S (=adj@X scaled) and X out ----------------
// 8 independent 256B gathers in flight per wave before the vmcnt drain.
__global__ void k_spmm(const u32* __restrict__ X2, const int* __restrict__ row_ptr,
                       const int* __restrict__ cols, const float* __restrict__ inv_deg,
                       u32* __restrict__ Sp, u32* __restrict__ Xp, int n) {
    int w = (int)((blockIdx.x * blockDim.x + threadIdx.x) >> 6);
    if (w >= n) return;
    int lane = threadIdx.x & 63;
    int beg = row_ptr[w], end = row_ptr[w + 1];
    float a0 = 0.f, a1 = 0.f;
    for (int j0 = beg; j0 < end; j0 += 64) {
        int cnt = end - j0; if (cnt > 64) cnt = 64;
        int myc = (lane < cnt) ? cols[j0 + lane] : 0;
        int j = 0;
        for (; j + 8 <= cnt; j += 8) {
            int c0 = __shfl(myc, j + 0);
            int c1 = __shfl(myc, j + 1);
            int c2 = __shfl(myc, j + 2);
            int c3 = __shfl(myc, j + 3);
            int c4 = __shfl(myc, j + 4);
            int c5 = __shfl(myc, j + 5);
            int c6 = __shfl(myc, j + 6);
            int c7 = __shfl(myc, j + 7);
            u32 p0 = X2[(size_t)c0 * 64 + lane];
            u32 p1 = X2[(size_t)c1 * 64 + lane];
            u32 p2 = X2[(size_t)c2 * 64 + lane];
            u32 p3 = X2[(size_t)c3 * 64 + lane];
            u32 p4 = X2[(size_t)c4 * 64 + lane];
            u32 p5 = X2[(size_t)c5 * 64 + lane];
            u32 p6 = X2[(size_t)c6 * 64 + lane];
            u32 p7 = X2[(size_t)c7 * 64 + lane];
            a0 += bf2f(p0 & 0xffffu) + bf2f(p1 & 0xffffu) + bf2f(p2 & 0xffffu) + bf2f(p3 & 0xffffu)
                + bf2f(p4 & 0xffffu) + bf2f(p5 & 0xffffu) + bf2f(p6 & 0xffffu) + bf2f(p7 & 0xffffu);
            a1 += bf2f(p0 >> 16) + bf2f(p1 >> 16) + bf2f(p2 >> 16) + bf2f(p3 >> 16)
                + bf2f(p4 >> 16) + bf2f(p5 >> 16) + bf2f(p6 >> 16) + bf2f(p7 >> 16);
        }
        for (; j + 4 <= cnt; j += 4) {
            int c0 = __shfl(myc, j + 0);
            int c1 = __shfl(myc, j + 1);
            int c2 = __shfl(myc, j + 2);
            int c3 = __shfl(myc, j + 3);
            u32 p0 = X2[(size_t)c0 * 64 + lane];
            u32 p1 = X2[(size_t)c1 * 64 + lane];
            u32 p2 = X2[(size_t)c2 * 64 + lane];
            u32 p3 = X2[(size_t)c3 * 64 + lane];
            a0 += bf2f(p0 & 0xffffu) + bf2f(p1 & 0xffffu) + bf2f(p2 & 0xffffu) + bf2f(p3 & 0xffffu);
            a1 += bf2f(p0 >> 16) + bf2f(p1 >> 16) + bf2f(p2 >> 16) + bf2f(p3 >> 16);
        }
        for (; j < cnt; ++j) {
            int c = __shfl(myc, j);
            u32 p = X2[(size_t)c * 64 + lane];
            a0 += bf2f(p & 0xffffu);
            a1 += bf2f(p >> 16);
        }
    }
    float s = inv_deg[w];
    a0 *= s; a1 *= s;
    u32 px = X2[(size_t)w * 64 + lane];
    int cc = lane >> 4, qq = (lane >> 2) & 3, jj = lane & 3;
    size_t dst = (size_t)(w >> 4) * 1024 + cc * 256 + qq * 64 + (w & 15) * 4 + jj;
    Sp[dst] = (u32)f2bf(a0) | ((u32)f2bf(a1) << 16);
    Xp[dst] = px;
}

// ---------------- fused GEMM + attention combine; A = {S, X}; W = [Wl, -Wh, Wh, Wm] ----------------
// out_low = S@Wl, out_high = S@(-Wh) + X@Wh, out_mlp = X@Wm.
// MT=4 (64 rows/block): ~84 VGPR -> 6 waves/SIMD; grid (n/64) ~ 1563 blocks -> 6 blocks/CU.  [R8: MT=8 gave 7.8% occupancy, 75 us]
template<int HOUT, int MT, bool L1>
__global__ __launch_bounds__(256)
void k_gemm_comb(const u16* __restrict__ Sp, const u16* __restrict__ Xp,
                 const u16* __restrict__ Wp,
                 const float* __restrict__ vl, const float* __restrict__ vh, const float* __restrict__ vm,
                 const float* __restrict__ att, int n,
                 u16* __restrict__ feaOut, float* __restrict__ fOut) {
    constexpr int KPG = HOUT / 64;
    constexpr int NTw = 3 * KPG;
    constexpr int ROWS = MT * 16;
    int w = threadIdx.x >> 6, lane = threadIdx.x & 63;
    int ln15 = lane & 15, lq = lane >> 4;
    int m0 = blockIdx.x * ROWS;

    f32x4 acc[MT][NTw];
#pragma unroll
    for (int mt = 0; mt < MT; ++mt)
#pragma unroll
        for (int k = 0; k < NTw; ++k) { f32x4 z = {0.f, 0.f, 0.f, 0.f}; acc[mt][k] = z; }

    for (int c = 0; c < 4; ++c) {
        short8 bl[KPG], bhn[KPG], bhp[KPG], bm[KPG];
#pragma unroll
        for (int kk = 0; kk < KPG; ++kk) {
            int Tl = w + kk * 4;
            size_t fo = (size_t)(Tl * 4 + c) * 512 + lane * 8;
            bl[kk]  = *(const short8*)(Wp + (size_t)0 * (HOUT * 128) + fo);
            bhn[kk] = *(const short8*)(Wp + (size_t)1 * (HOUT * 128) + fo);
            bhp[kk] = *(const short8*)(Wp + (size_t)2 * (HOUT * 128) + fo);
            bm[kk]  = *(const short8*)(Wp + (size_t)3 * (HOUT * 128) + fo);
        }
#pragma unroll
        for (int mt = 0; mt < MT; ++mt) {
            size_t off = ((size_t)((m0 >> 4) + mt) * 4 + c) * 512 + lane * 8;
            short8 as = *(const short8*)(Sp + off);
            short8 ax = *(const short8*)(Xp + off);
#pragma unroll
            for (int kk = 0; kk < KPG; ++kk) {
                acc[mt][0 * KPG + kk] = __builtin_amdgcn_mfma_f32_16x16x32_bf16(as, bl[kk], acc[mt][0 * KPG + kk], 0, 0, 0);
                acc[mt][1 * KPG + kk] = __builtin_amdgcn_mfma_f32_16x16x32_bf16(as, bhn[kk], acc[mt][1 * KPG + kk], 0, 0, 0);
                acc[mt][1 * KPG + kk] = __builtin_amdgcn_mfma_f32_16x16x32_bf16(ax, bhp[kk], acc[mt][1 * KPG + kk], 0, 0, 0);
                acc[mt][2 * KPG + kk] = __builtin_amdgcn_mfma_f32_16x16x32_bf16(ax, bm[kk], acc[mt][2 * KPG + kk], 0, 0, 0);
            }
        }
    }

    float vval[NTw];
#pragma unroll
    for (int k = 0; k < NTw; ++k) {
        int g = k / KPG, kk = k % KPG;
        int col = w * 16 + kk * 64 + ln15;
        vval[k] = (g == 0 ? vl : (g == 1 ? vh : vm))[col];
    }

    __shared__ float part[4][3][ROWS];
    __shared__ float wgt[ROWS][3];
#pragma unroll
    for (int mt = 0; mt < MT; ++mt) {
        float pdg[3][4];
#pragma unroll
        for (int g = 0; g < 3; ++g)
#pragma unroll
            for (int r = 0; r < 4; ++r) pdg[g][r] = 0.f;
#pragma unroll
        for (int k = 0; k < NTw; ++k) {
            int g = k / KPG;
#pragma unroll
            for (int r = 0; r < 4; ++r)
                pdg[g][r] += fmaxf(acc[mt][k][r], 0.f) * vval[k];
        }
#pragma unroll
        for (int off = 1; off < 16; off <<= 1)
#pragma unroll
            for (int g = 0; g < 3; ++g)
#pragma unroll
                for (int r = 0; r < 4; ++r)
                    pdg[g][r] += __shfl_xor(pdg[g][r], off);
        if (ln15 == 0) {
#pragma unroll
            for (int g = 0; g < 3; ++g)
#pragma unroll
                for (int r = 0; r < 4; ++r)
                    part[w][g][mt * 16 + lq * 4 + r] = pdg[g][r];
        }
    }
    __syncthreads();
    if (threadIdx.x < ROWS) {
        int row = threadIdx.x;
        float d0 = part[0][0][row] + part[1][0][row] + part[2][0][row] + part[3][0][row];
        float d1 = part[0][1][row] + part[1][1][row] + part[2][1][row] + part[3][1][row];
        float d2 = part[0][2][row] + part[1][2][row] + part[2][2][row] + part[3][2][row];
        float s0 = 1.f / (1.f + __expf(-d0));
        float s1 = 1.f / (1.f + __expf(-d1));
        float s2 = 1.f / (1.f + __expf(-d2));
        float a0 = (s0 * att[0] + s1 * att[3] + s2 * att[6]) * (1.f / 3.f);
        float a1 = (s0 * att[1] + s1 * att[4] + s2 * att[7]) * (1.f / 3.f);
        float a2 = (s0 * att[2] + s1 * att[5] + s2 * att[8]) * (1.f / 3.f);
        float mx = fmaxf(a0, fmaxf(a1, a2));
        float e0 = __expf(a0 - mx), e1 = __expf(a1 - mx), e2 = __expf(a2 - mx);
        float inv = 3.f / (e0 + e1 + e2);
        wgt[row][0] = e0 * inv;
        wgt[row][1] = e1 * inv;
        wgt[row][2] = e2 * inv;
    }
    __syncthreads();

#pragma unroll
    for (int mt = 0; mt < MT; ++mt)
#pragma unroll
        for (int kk = 0; kk < KPG; ++kk)
#pragma unroll
            for (int r = 0; r < 4; ++r) {
                int row_local = mt * 16 + lq * 4 + r;
                int row = m0 + row_local;
                if (row < n) {
                    int col = w * 16 + kk * 64 + ln15;
                    float w0 = wgt[row_local][0], w1 = wgt[row_local][1], w2 = wgt[row_local][2];
                    float ol = fmaxf(acc[mt][0 * KPG + kk][r], 0.f);
                    float oh = fmaxf(acc[mt][1 * KPG + kk][r], 0.f);
                    float om = fmaxf(acc[mt][2 * KPG + kk][r], 0.f);
                    float val = w0 * ol + w1 * oh + w2 * om;
                    if (L1)
                        feaOut[(size_t)row * HOUT + col] = f2bf(fmaxf(val, 0.f));
                    else
                        fOut[(size_t)row * HOUT + col] = val;
                }
            }
}

extern "C" void kernel_launch(void* const* d_in, const int* in_sizes, int n_in,
                              void* d_out, int out_size, void* d_ws, size_t ws_size,
                              hipStream_t stream) {
    const int F = 128;
    int n = in_sizes[0] / F;
    int e = in_sizes[1] / 2;
    int n64 = (n + 63) & ~63;
    int nbuck = (n + (1 << BSHIFT) - 1) >> BSHIFT;
    const float* x = (const float*)d_in[0];
    const int* ei = (const int*)d_in[1];
    const int* erow = ei;
    const int* ecol = ei + e;
    const float *Wl1 = (const float*)d_in[2], *Wh1 = (const float*)d_in[3], *Wm1 = (const float*)d_in[4];
    const float *vl1 = (const float*)d_in[5], *vh1 = (const float*)d_in[6], *vm1 = (const float*)d_in[7];
    const float* att1 = (const float*)d_in[8];
    const float *Wl2 = (const float*)d_in[9], *Wh2 = (const float*)d_in[10], *Wm2 = (const float*)d_in[11];
    const float *vl2 = (const float*)d_in[12], *vh2 = (const float*)d_in[13], *vm2 = (const float*)d_in[14];
    const float* att2 = (const float*)d_in[15];
    float* out = (float*)d_out;

    char* ws = (char*)d_ws;
    size_t off = 0;
    auto alloc = [&](size_t b) -> void* {
        void* p = ws + off;
        off = (off + b + 255) & ~(size_t)255;
        return p;
    };
    int* deg = (int*)alloc((size_t)n * 4);
    int* row_ptr = (int*)alloc((size_t)(n + 1) * 4);
    float* inv_deg = (float*)alloc((size_t)n * 4);
    int* bsum = (int*)alloc(1024);
    int* boff = (int*)alloc(1024);
    int* gcursor = (int*)alloc(MAXBUCK * 4);
    u32* bedge = (u32*)alloc((size_t)e * 4);
    int* cols = (int*)alloc((size_t)e * 4);
    u32* Sp = (u32*)alloc((size_t)n64 * 64 * 4);
    u32* Xp = (u32*)alloc((size_t)n64 * 64 * 4);
    u32* Fp = (u32*)alloc((size_t)n64 * 64 * 4);
    u16* Xb = (u16*)alloc((size_t)n * 128 * 2);
    u16* fea = (u16*)alloc((size_t)n * 128 * 2);
    u16* Wp1 = (u16*)alloc((size_t)4 * 128 * 128 * 2);
    u16* Wp2 = (u16*)alloc((size_t)4 * 64 * 128 * 2);
    (void)ws_size; (void)n_in; (void)out_size;

    const int tb = 256;
    k_prep<<<CASTBLK + 16, 256, 0, stream>>>((const float4*)x, (u32*)Xb, (long)n * 32,
                                             Wl1, Wh1, Wm1, Wl2, Wh2, Wm2, Wp1, Wp2);

    hipMemsetAsync(deg, 0, (size_t)n * 4, stream);
    k_deg<<<(e + tb - 1) / tb, tb, 0, stream>>>(erow, e, deg);
    int nb = (n + 1023) / 1024;
    k_scan_a<<<nb, 256, 0, stream>>>(deg, n, bsum);
    k_scan_b<<<1, 256, 0, stream>>>(bsum, nb, boff);
    k_scan_c<<<nb, 256, 0, stream>>>(deg, n, boff, row_ptr, inv_deg, gcursor);

    k_bscatter<<<256, 256, 0, stream>>>(erow, ecol, e, nbuck, gcursor, bedge);
    k_bfill<<<nbuck, 256, 0, stream>>>(bedge, row_ptr, n, cols);

    int wb = (n + 3) / 4;
    int gb = n64 / 64;

    // layer 1
    k_spmm<<<wb, 256, 0, stream>>>((const u32*)Xb, row_ptr, cols, inv_deg, Sp, Xp, n);
    k_gemm_comb<128, 4, true><<<gb, 256, 0, stream>>>((const u16*)Sp, (const u16*)Xp,
                                                      Wp1, vl1, vh1, vm1, att1, n, fea, nullptr);

    // layer 2
    k_spmm<<<wb, 256, 0, stream>>>((const u32*)fea, row_ptr, cols, inv_deg, Sp, Fp, n);
    k_gemm_comb<64, 4, false><<<gb, 256, 0, stream>>>((const u16*)Sp, (const u16*)Fp,
                                                      Wp2, vl2, vh2, vm2, att2, n, nullptr, out);
}